// Round 1
// baseline (17623.624 us; speedup 1.0000x reference)
//
#include <hip/hip_runtime.h>
#include <math.h>

#define HIDDIM 512
#define BATCH  512
#define NIN    128
#define TSTEPS 128
#define HORIZN 32

#define BM 32
#define BU 32
#define BKT 32

__device__ __forceinline__ float sigf(float x) { return 1.0f / (1.0f + expf(-x)); }

// Fused LSTM cell step: gates = x @ Wih^T + h @ Whh^T + (bih+bhh), then pointwise.
// Each WG computes a 32(b) x 32(u) tile of the hidden state for ALL 4 gates.
__global__ __launch_bounds__(256) void lstm_cell(
    const float* __restrict__ x, long ldx, int Kx,
    const float* __restrict__ Wih,            // [4*HID, Kx]
    const float* __restrict__ h_in,           // [B, HID]
    const float* __restrict__ Whh,            // [4*HID, HID]
    const float* __restrict__ bih, const float* __restrict__ bhh,
    float* __restrict__ c,                    // [B, HID] in/out (in-place safe: per-element)
    float* __restrict__ h_out,                // [B, HID]
    const float* __restrict__ mask_h,         // nullable [B, HID]
    const float* __restrict__ mask_c,         // nullable [B, HID]
    float* __restrict__ hd_out)               // nullable: if set, h_out unmasked, hd_out = h*mask_h
{
    __shared__ float Xs[BKT][BM + 1];
    __shared__ float Ws[4][BKT][BU + 1];

    const int b0 = blockIdx.x * BM;
    const int u0 = blockIdx.y * BU;
    const int tid = threadIdx.x;
    const int tx = tid & 15;   // u
    const int ty = tid >> 4;   // b

    float acc[4][2][2];
#pragma unroll
    for (int g = 0; g < 4; ++g)
#pragma unroll
        for (int i = 0; i < 2; ++i)
#pragma unroll
            for (int j = 0; j < 2; ++j) acc[g][i][j] = 0.f;

    const int lrow = tid >> 3;        // 0..31
    const int lcol = (tid & 7) * 4;   // 0..28

    for (int phase = 0; phase < 2; ++phase) {
        const float* A  = phase ? h_in : x;
        const long  lda = phase ? (long)HIDDIM : ldx;
        const float* W  = phase ? Whh : Wih;
        const long  ldw = phase ? (long)HIDDIM : (long)Kx;
        const int   K   = phase ? HIDDIM : Kx;
        for (int k0 = 0; k0 < K; k0 += BKT) {
            __syncthreads();
            {
                const float4 v = *reinterpret_cast<const float4*>(A + (long)(b0 + lrow) * lda + k0 + lcol);
                Xs[lcol + 0][lrow] = v.x; Xs[lcol + 1][lrow] = v.y;
                Xs[lcol + 2][lrow] = v.z; Xs[lcol + 3][lrow] = v.w;
            }
#pragma unroll
            for (int g = 0; g < 4; ++g) {
                const float4 v = *reinterpret_cast<const float4*>(W + (long)(g * HIDDIM + u0 + lrow) * ldw + k0 + lcol);
                Ws[g][lcol + 0][lrow] = v.x; Ws[g][lcol + 1][lrow] = v.y;
                Ws[g][lcol + 2][lrow] = v.z; Ws[g][lcol + 3][lrow] = v.w;
            }
            __syncthreads();
#pragma unroll
            for (int k = 0; k < BKT; ++k) {
                const float a0 = Xs[k][ty * 2 + 0];
                const float a1 = Xs[k][ty * 2 + 1];
#pragma unroll
                for (int g = 0; g < 4; ++g) {
                    const float w0 = Ws[g][k][tx * 2 + 0];
                    const float w1 = Ws[g][k][tx * 2 + 1];
                    acc[g][0][0] += a0 * w0;
                    acc[g][0][1] += a0 * w1;
                    acc[g][1][0] += a1 * w0;
                    acc[g][1][1] += a1 * w1;
                }
            }
        }
    }

#pragma unroll
    for (int i = 0; i < 2; ++i) {
        const int b = b0 + ty * 2 + i;
#pragma unroll
        for (int j = 0; j < 2; ++j) {
            const int u = u0 + tx * 2 + j;
            const float gi = acc[0][i][j] + bih[u]              + bhh[u];
            const float gf = acc[1][i][j] + bih[HIDDIM + u]     + bhh[HIDDIM + u];
            const float gg = acc[2][i][j] + bih[2 * HIDDIM + u] + bhh[2 * HIDDIM + u];
            const float go = acc[3][i][j] + bih[3 * HIDDIM + u] + bhh[3 * HIDDIM + u];
            const long idx = (long)b * HIDDIM + u;
            float cn = sigf(gf) * c[idx] + sigf(gi) * tanhf(gg);
            float hn = sigf(go) * tanhf(cn);         // h from UNMASKED c (per reference)
            if (mask_c) cn *= mask_c[idx];
            c[idx] = cn;
            if (hd_out) {
                h_out[idx]  = hn;                    // recurrent state unmasked
                hd_out[idx] = hn * mask_h[idx];      // layer-1 input masked
            } else {
                if (mask_h) hn *= mask_h[idx];
                h_out[idx] = hn;
            }
        }
    }
}

// pred = h @ Wp^T + bp ; writes pred buffer and scatters into out[:, s]
__global__ __launch_bounds__(256) void proj_kernel(
    const float* __restrict__ h,    // [B, HID]
    const float* __restrict__ Wp,   // [NIN, HID]
    const float* __restrict__ bp,   // [NIN]
    float* __restrict__ pred,       // [B, NIN]
    float* __restrict__ out,        // [B*NIN, HOR]
    int s)
{
    __shared__ float Hs[BKT][BM + 1];
    __shared__ float Ps[BKT][BU + 1];
    const int b0 = blockIdx.x * BM;
    const int n0 = blockIdx.y * BU;
    const int tid = threadIdx.x;
    const int tx = tid & 15;
    const int ty = tid >> 4;
    const int lrow = tid >> 3;
    const int lcol = (tid & 7) * 4;

    float acc[2][2] = {{0.f, 0.f}, {0.f, 0.f}};
    for (int k0 = 0; k0 < HIDDIM; k0 += BKT) {
        __syncthreads();
        {
            const float4 v = *reinterpret_cast<const float4*>(h + (long)(b0 + lrow) * HIDDIM + k0 + lcol);
            Hs[lcol + 0][lrow] = v.x; Hs[lcol + 1][lrow] = v.y;
            Hs[lcol + 2][lrow] = v.z; Hs[lcol + 3][lrow] = v.w;
        }
        {
            const float4 v = *reinterpret_cast<const float4*>(Wp + (long)(n0 + lrow) * HIDDIM + k0 + lcol);
            Ps[lcol + 0][lrow] = v.x; Ps[lcol + 1][lrow] = v.y;
            Ps[lcol + 2][lrow] = v.z; Ps[lcol + 3][lrow] = v.w;
        }
        __syncthreads();
#pragma unroll
        for (int k = 0; k < BKT; ++k) {
            const float a0 = Hs[k][ty * 2 + 0];
            const float a1 = Hs[k][ty * 2 + 1];
            const float w0 = Ps[k][tx * 2 + 0];
            const float w1 = Ps[k][tx * 2 + 1];
            acc[0][0] += a0 * w0; acc[0][1] += a0 * w1;
            acc[1][0] += a1 * w0; acc[1][1] += a1 * w1;
        }
    }
#pragma unroll
    for (int i = 0; i < 2; ++i) {
        const int b = b0 + ty * 2 + i;
#pragma unroll
        for (int j = 0; j < 2; ++j) {
            const int n = n0 + tx * 2 + j;
            const float v = acc[i][j] + bp[n];
            pred[b * NIN + n] = v;
            out[(long)(b * NIN + n) * HORIZN + s] = v;
        }
    }
}

extern "C" void kernel_launch(void* const* d_in, const int* in_sizes, int n_in,
                              void* d_out, int out_size, void* d_ws, size_t ws_size,
                              hipStream_t stream) {
    const float* window = (const float*)d_in[0];
    const float* Wih0 = (const float*)d_in[1];
    const float* Whh0 = (const float*)d_in[2];
    const float* bih0 = (const float*)d_in[3];
    const float* bhh0 = (const float*)d_in[4];
    const float* Wih1 = (const float*)d_in[5];
    const float* Whh1 = (const float*)d_in[6];
    const float* bih1 = (const float*)d_in[7];
    const float* bhh1 = (const float*)d_in[8];
    const float* Wc1i = (const float*)d_in[9];
    const float* Wc1h = (const float*)d_in[10];
    const float* bc1i = (const float*)d_in[11];
    const float* bc1h = (const float*)d_in[12];
    const float* Wc2i = (const float*)d_in[13];
    const float* Wc2h = (const float*)d_in[14];
    const float* bc2i = (const float*)d_in[15];
    const float* bc2h = (const float*)d_in[16];
    const float* Wp   = (const float*)d_in[17];
    const float* bp   = (const float*)d_in[18];
    const float* enc_mask   = (const float*)d_in[19];
    const float* dec_h_mask = (const float*)d_in[20];
    const float* dec_c_mask = (const float*)d_in[21];

    float* ws = (float*)d_ws;
    const size_t SB = (size_t)BATCH * HIDDIM;   // 262144 floats
    // layout: [hA0, cA, hB0, cB] (zeroed) [hA1, hB1, hd, pred]
    float* hA0 = ws;
    float* cA  = ws + 1 * SB;
    float* hB0 = ws + 2 * SB;
    float* cB  = ws + 3 * SB;
    float* hA1 = ws + 4 * SB;
    float* hB1 = ws + 5 * SB;
    float* hd  = ws + 6 * SB;
    float* pred = ws + 7 * SB;

    hipMemsetAsync(d_ws, 0, 4 * SB * sizeof(float), stream);

    float* hA[2] = {hA0, hA1};
    float* hB[2] = {hB0, hB1};
    int ca = 0, cb = 0;

    dim3 grid(BATCH / BM, HIDDIM / BU);     // 16 x 16
    dim3 block(256);
    dim3 pgrid(BATCH / BM, NIN / BU);       // 16 x 4
    float* out = (float*)d_out;

    // ---- encoder: layers 0 and 1 in t-lockstep ----
    for (int t = 0; t < TSTEPS; ++t) {
        lstm_cell<<<grid, block, 0, stream>>>(
            window + (long)t * NIN, (long)TSTEPS * NIN, NIN,
            Wih0, hA[ca], Whh0, bih0, bhh0,
            cA, hA[ca ^ 1],
            enc_mask + (size_t)t * SB, nullptr, hd);
        ca ^= 1;
        lstm_cell<<<grid, block, 0, stream>>>(
            hd, HIDDIM, HIDDIM,
            Wih1, hB[cb], Whh1, bih1, bhh1,
            cB, hB[cb ^ 1],
            nullptr, nullptr, nullptr);
        cb ^= 1;
    }

    // ---- decoder ----
    for (int s = 0; s < HORIZN - 1; ++s) {
        proj_kernel<<<pgrid, block, 0, stream>>>(hB[cb], Wp, bp, pred, out, s);
        lstm_cell<<<grid, block, 0, stream>>>(
            pred, NIN, NIN,
            Wc1i, hA[ca], Wc1h, bc1i, bc1h,
            cA, hA[ca ^ 1],
            dec_h_mask + (size_t)s * SB, dec_c_mask + (size_t)s * SB, nullptr);
        ca ^= 1;
        lstm_cell<<<grid, block, 0, stream>>>(
            hA[ca], HIDDIM, HIDDIM,
            Wc2i, hB[cb], Wc2h, bc2i, bc2h,
            cB, hB[cb ^ 1],
            nullptr, nullptr, nullptr);
        cb ^= 1;
    }
    proj_kernel<<<pgrid, block, 0, stream>>>(hB[cb], Wp, bp, pred, out, HORIZN - 1);
}

// Round 2
// 9847.614 us; speedup vs baseline: 1.7896x; 1.7896x over previous
//
#include <hip/hip_runtime.h>
#include <math.h>

#define HID 512
#define BAT 512
#define NIN 128
#define TST 128
#define HOR 32

using bf16x8 = __attribute__((ext_vector_type(8))) __bf16;
using f32x4  = __attribute__((ext_vector_type(4))) float;

__device__ __forceinline__ float sigf(float x) { return 1.0f / (1.0f + expf(-x)); }

__device__ __forceinline__ short f2bf(float x) {
    union { float f; unsigned u; } v; v.f = x;
    unsigned r = (v.u + 0x7FFFu + ((v.u >> 16) & 1u)) >> 16;
    return (short)r;
}
__device__ __forceinline__ float bf2f(short s) {
    union { unsigned u; float f; } v; v.u = ((unsigned)(unsigned short)s) << 16;
    return v.f;
}

__device__ __forceinline__ void async16(const void* g, void* l) {
    __builtin_amdgcn_global_load_lds(
        (const __attribute__((address_space(1))) void*)g,
        (__attribute__((address_space(3))) void*)l, 16, 0, 0);
}

// ---------------- prep kernels ----------------

// W2 row n' (permuted: n' = nb*128 + gate*32 + uu  <->  orig row gate*512 + nb*32 + uu)
// cols: [0,Kx)=Wih_hi  [Kx,2Kx)=Wih_lo  [2Kx,2Kx+512)=Whh_hi  [2Kx+512,Kp)=Whh_lo
__global__ __launch_bounds__(256) void prep_w(const float* __restrict__ Wih,
                                              const float* __restrict__ Whh,
                                              short* __restrict__ W2, int Kx, int Kp) {
    size_t i = (size_t)blockIdx.x * 256 + threadIdx.x;
    if (i >= (size_t)2048 * Kp) return;
    int np = (int)(i / Kp), kp = (int)(i % Kp);
    int nb = np >> 7, gate = (np >> 5) & 3, uu = np & 31;
    int on = gate * HID + nb * 32 + uu;
    float w; bool islo = false;
    if (kp < Kx)                { w = Wih[(size_t)on * Kx + kp]; }
    else if (kp < 2 * Kx)       { w = Wih[(size_t)on * Kx + (kp - Kx)]; islo = true; }
    else if (kp < 2 * Kx + HID) { w = Whh[(size_t)on * HID + (kp - 2 * Kx)]; }
    else                        { w = Whh[(size_t)on * HID + (kp - 2 * Kx - HID)]; islo = true; }
    short hi = f2bf(w);
    W2[i] = islo ? f2bf(w - bf2f(hi)) : hi;
}

// x2[tl][b][0..127]=hi, [128..255]=lo  from window[b][t0+tl][n]
__global__ __launch_bounds__(256) void prep_x(const float* __restrict__ window,
                                              short* __restrict__ x2, int t0, int nt) {
    size_t i = (size_t)blockIdx.x * 256 + threadIdx.x;
    if (i >= (size_t)nt * BAT * NIN) return;
    int n = (int)(i & 127);
    int b = (int)((i >> 7) & 511);
    int tl = (int)(i >> 16);
    float x = window[(size_t)b * (TST * NIN) + (size_t)(t0 + tl) * NIN + n];
    short hi = f2bf(x);
    short* dst = x2 + (size_t)tl * (BAT * 256) + (size_t)b * 256;
    dst[n] = hi;
    dst[128 + n] = f2bf(x - bf2f(hi));
}

// ---------------- fused MFMA LSTM cell ----------------

struct CellDesc {
    const short* a0; long lda0; int len0;  // segment 0 of A (bf16 hi|lo), cols [0,len0)
    const short* a1;                        // segment 1: recurrent h2 [B][1024]
    const short* W2; int Kp;                // permuted weights [2048][Kp]
    const float* bih; const float* bhh;     // original [4*512]
    float* c;                               // [B][512] in/out
    const float* mask_h; const float* mask_c;
    short* h2_out;                          // [B][1024] = (h*mask_h) as hi|lo
    short* h2_aux; const float* mask_aux;   // nullable: h*mask_aux as hi|lo
    float* h_f32;                           // nullable: unmasked h fp32
};

__global__ __launch_bounds__(256) void cell_kernel(CellDesc dA, CellDesc dB) {
    const CellDesc d = (blockIdx.z == 0) ? dA : dB;
    __shared__ __align__(16) char smem[67584];   // A 8KB | B 8KB, reused as gates [128][132] f32

    const int tid = threadIdx.x;
    const int m0 = blockIdx.x * 128;
    const int n0 = blockIdx.y * 128;
    const int lane = tid & 63, wid = tid >> 6;
    const int moff = (wid >> 1) * 64, noff = (wid & 1) * 64;

    f32x4 acc[4][4];
#pragma unroll
    for (int mi = 0; mi < 4; ++mi)
#pragma unroll
        for (int ni = 0; ni < 4; ++ni) acc[mi][ni] = (f32x4){0.f, 0.f, 0.f, 0.f};

    const int nkc = d.Kp >> 5;
    const int lrow = lane & 15;
    const int lko = (lane >> 4) << 4;      // byte offset of k-group within 64B row

    for (int kc = 0; kc < nkc; ++kc) {
        const int k0 = kc << 5;
        __syncthreads();
#pragma unroll
        for (int r = 0; r < 2; ++r) {
            const int idx = tid + (r << 8);
            const int row = idx >> 2;
            const int kg = k0 + ((idx & 3) << 3);
            if (k0 < d.len0)
                async16(d.a0 + (size_t)(m0 + row) * d.lda0 + kg, smem + idx * 16);
            else
                async16(d.a1 + (size_t)(m0 + row) * 1024 + (kg - d.len0), smem + idx * 16);
            async16(d.W2 + (size_t)(n0 + row) * d.Kp + kg, smem + 8192 + idx * 16);
        }
        __syncthreads();

        bf16x8 fa[4], fb[4];
#pragma unroll
        for (int mi = 0; mi < 4; ++mi)
            fa[mi] = *(const bf16x8*)(smem + (moff + mi * 16 + lrow) * 64 + lko);
#pragma unroll
        for (int ni = 0; ni < 4; ++ni)
            fb[ni] = *(const bf16x8*)(smem + 8192 + (noff + ni * 16 + lrow) * 64 + lko);
#pragma unroll
        for (int mi = 0; mi < 4; ++mi)
#pragma unroll
            for (int ni = 0; ni < 4; ++ni)
                acc[mi][ni] = __builtin_amdgcn_mfma_f32_16x16x32_bf16(fa[mi], fb[ni], acc[mi][ni], 0, 0, 0);
    }

    // dump gates to LDS (overlaps A/B regions — safe after barrier)
    __syncthreads();
    float* gl = (float*)smem;
#pragma unroll
    for (int mi = 0; mi < 4; ++mi)
#pragma unroll
        for (int ni = 0; ni < 4; ++ni)
#pragma unroll
            for (int r = 0; r < 4; ++r)
                gl[(moff + mi * 16 + ((lane >> 4) << 2) + r) * 132 + (noff + ni * 16 + (lane & 15))] = acc[mi][ni][r];
    __syncthreads();

    // pointwise epilogue: this block owns b in [m0,m0+128), u in [by*32, by*32+32)
    const int uu = tid & 31;
    const int bg = tid >> 5;
    const int u = blockIdx.y * 32 + uu;
    const float bi  = d.bih[u]           + d.bhh[u];
    const float bff = d.bih[HID + u]     + d.bhh[HID + u];
    const float bgg = d.bih[2 * HID + u] + d.bhh[2 * HID + u];
    const float boo = d.bih[3 * HID + u] + d.bhh[3 * HID + u];
#pragma unroll
    for (int i = 0; i < 16; ++i) {
        const int lb = bg * 16 + i;
        const int b = m0 + lb;
        const size_t idx = (size_t)b * HID + u;
        const float* row = gl + (size_t)lb * 132;
        const float gi = row[uu] + bi;
        const float gf = row[32 + uu] + bff;
        const float gg = row[64 + uu] + bgg;
        const float go = row[96 + uu] + boo;
        const float cv = d.c[idx];
        const float cn = sigf(gf) * cv + sigf(gi) * tanhf(gg);
        const float h  = sigf(go) * tanhf(cn);
        d.c[idx] = d.mask_c ? cn * d.mask_c[idx] : cn;
        const float hm = d.mask_h ? h * d.mask_h[idx] : h;
        const short hh = f2bf(hm);
        d.h2_out[(size_t)b * 1024 + u] = hh;
        d.h2_out[(size_t)b * 1024 + HID + u] = f2bf(hm - bf2f(hh));
        if (d.h2_aux) {
            const float ha = h * d.mask_aux[idx];
            const short ah = f2bf(ha);
            d.h2_aux[(size_t)b * 1024 + u] = ah;
            d.h2_aux[(size_t)b * 1024 + HID + u] = f2bf(ha - bf2f(ah));
        }
        if (d.h_f32) d.h_f32[idx] = h;
    }
}

// ---------------- projection (fp32, small) ----------------

#define BM 32
#define BU 32
#define BKT 32

__global__ __launch_bounds__(256) void proj_kernel(
    const float* __restrict__ h, const float* __restrict__ Wp, const float* __restrict__ bp,
    short* __restrict__ pred2, float* __restrict__ out, int s) {
    __shared__ float Hs[BKT][BM + 1];
    __shared__ float Ps[BKT][BU + 1];
    const int b0 = blockIdx.x * BM;
    const int n0 = blockIdx.y * BU;
    const int tid = threadIdx.x;
    const int tx = tid & 15;
    const int ty = tid >> 4;
    const int lrow = tid >> 3;
    const int lcol = (tid & 7) * 4;

    float acc[2][2] = {{0.f, 0.f}, {0.f, 0.f}};
    for (int k0 = 0; k0 < HID; k0 += BKT) {
        __syncthreads();
        {
            const float4 v = *reinterpret_cast<const float4*>(h + (size_t)(b0 + lrow) * HID + k0 + lcol);
            Hs[lcol + 0][lrow] = v.x; Hs[lcol + 1][lrow] = v.y;
            Hs[lcol + 2][lrow] = v.z; Hs[lcol + 3][lrow] = v.w;
        }
        {
            const float4 v = *reinterpret_cast<const float4*>(Wp + (size_t)(n0 + lrow) * HID + k0 + lcol);
            Ps[lcol + 0][lrow] = v.x; Ps[lcol + 1][lrow] = v.y;
            Ps[lcol + 2][lrow] = v.z; Ps[lcol + 3][lrow] = v.w;
        }
        __syncthreads();
#pragma unroll
        for (int k = 0; k < BKT; ++k) {
            const float a0 = Hs[k][ty * 2 + 0];
            const float a1 = Hs[k][ty * 2 + 1];
            const float w0 = Ps[k][tx * 2 + 0];
            const float w1 = Ps[k][tx * 2 + 1];
            acc[0][0] += a0 * w0; acc[0][1] += a0 * w1;
            acc[1][0] += a1 * w0; acc[1][1] += a1 * w1;
        }
    }
#pragma unroll
    for (int i = 0; i < 2; ++i) {
        const int b = b0 + ty * 2 + i;
#pragma unroll
        for (int j = 0; j < 2; ++j) {
            const int n = n0 + tx * 2 + j;
            const float v = acc[i][j] + bp[n];
            out[(size_t)(b * NIN + n) * HOR + s] = v;
            const short vh = f2bf(v);
            pred2[(size_t)b * 256 + n] = vh;
            pred2[(size_t)b * 256 + 128 + n] = f2bf(v - bf2f(vh));
        }
    }
}

// ---------------- host ----------------

extern "C" void kernel_launch(void* const* d_in, const int* in_sizes, int n_in,
                              void* d_out, int out_size, void* d_ws, size_t ws_size,
                              hipStream_t stream) {
    (void)in_sizes; (void)n_in; (void)out_size;
    const float* window = (const float*)d_in[0];
    const float* Wih0 = (const float*)d_in[1];
    const float* Whh0 = (const float*)d_in[2];
    const float* bih0 = (const float*)d_in[3];
    const float* bhh0 = (const float*)d_in[4];
    const float* Wih1 = (const float*)d_in[5];
    const float* Whh1 = (const float*)d_in[6];
    const float* bih1 = (const float*)d_in[7];
    const float* bhh1 = (const float*)d_in[8];
    const float* Wc1i = (const float*)d_in[9];
    const float* Wc1h = (const float*)d_in[10];
    const float* bc1i = (const float*)d_in[11];
    const float* bc1h = (const float*)d_in[12];
    const float* Wc2i = (const float*)d_in[13];
    const float* Wc2h = (const float*)d_in[14];
    const float* bc2i = (const float*)d_in[15];
    const float* bc2h = (const float*)d_in[16];
    const float* Wp   = (const float*)d_in[17];
    const float* bp   = (const float*)d_in[18];
    const float* enc_mask   = (const float*)d_in[19];
    const float* dec_h_mask = (const float*)d_in[20];
    const float* dec_c_mask = (const float*)d_in[21];
    float* out = (float*)d_out;

    char* base = (char*)d_ws;
    size_t off = 0;
    auto take = [&](size_t bytes) -> char* {
        off = (off + 255) & ~(size_t)255;
        char* r = base + off; off += bytes; return r;
    };
    short* W2e0 = (short*)take((size_t)2048 * 1280 * 2);
    short* W2e1 = (short*)take((size_t)2048 * 2048 * 2);
    short* W2d1 = (short*)take((size_t)2048 * 1280 * 2);
    short* W2d2 = (short*)take((size_t)2048 * 2048 * 2);
    short* hA2[2] = {(short*)take((size_t)BAT * 1024 * 2), (short*)take((size_t)BAT * 1024 * 2)};
    short* hB2[2] = {(short*)take((size_t)BAT * 1024 * 2), (short*)take((size_t)BAT * 1024 * 2)};
    short* hd2[2] = {(short*)take((size_t)BAT * 1024 * 2), (short*)take((size_t)BAT * 1024 * 2)};
    float* cA   = (float*)take((size_t)BAT * HID * 4);
    float* cB   = (float*)take((size_t)BAT * HID * 4);
    float* hf32 = (float*)take((size_t)BAT * HID * 4);
    short* pred2 = (short*)take((size_t)BAT * 256 * 2);
    const size_t off_nox2 = off;
    short* X2 = (short*)take((size_t)TST * BAT * 256 * 2);
    bool fullX2 = (ws_size >= off);
    short* x2step = nullptr;
    if (!fullX2) { off = off_nox2; x2step = (short*)take((size_t)BAT * 256 * 2); }

    const size_t SB = (size_t)BAT * HID;

    // prep: weight/input conversion + state zero-init (re-done every call; deterministic)
    prep_w<<<(2048 * 1280 + 255) / 256, 256, 0, stream>>>(Wih0, Whh0, W2e0, NIN, 1280);
    prep_w<<<(2048 * 2048 + 255) / 256, 256, 0, stream>>>(Wih1, Whh1, W2e1, HID, 2048);
    prep_w<<<(2048 * 1280 + 255) / 256, 256, 0, stream>>>(Wc1i, Wc1h, W2d1, NIN, 1280);
    prep_w<<<(2048 * 2048 + 255) / 256, 256, 0, stream>>>(Wc2i, Wc2h, W2d2, HID, 2048);
    if (fullX2)
        prep_x<<<(int)(((size_t)TST * BAT * NIN + 255) / 256), 256, 0, stream>>>(window, X2, 0, TST);
    hipMemsetAsync(hA2[0], 0, (size_t)BAT * 1024 * 2, stream);
    hipMemsetAsync(hB2[0], 0, (size_t)BAT * 1024 * 2, stream);
    hipMemsetAsync(cA, 0, (size_t)BAT * HID * 4, stream);
    hipMemsetAsync(cB, 0, (size_t)BAT * HID * 4, stream);

    dim3 block(256);
    dim3 pgrid(BAT / BM, NIN / BU);

    // ---- encoder: layer0(t) paired with layer1(t-1) in one launch (independent) ----
    for (int tt = 0; tt <= TST; ++tt) {
        const bool has1 = (tt >= 1), has0 = (tt < TST);
        CellDesc dc1{}, dc0{};
        if (has1) {
            const int t = tt - 1;
            dc1.a0 = hd2[t & 1]; dc1.lda0 = 1024; dc1.len0 = 1024;
            dc1.a1 = hB2[t & 1];
            dc1.W2 = W2e1; dc1.Kp = 2048;
            dc1.bih = bih1; dc1.bhh = bhh1;
            dc1.c = cB; dc1.mask_h = nullptr; dc1.mask_c = nullptr;
            dc1.h2_out = hB2[(t + 1) & 1];
            dc1.h2_aux = nullptr; dc1.mask_aux = nullptr;
            dc1.h_f32 = hf32;
        }
        if (has0) {
            const int t = tt;
            if (!fullX2)
                prep_x<<<(int)(((size_t)BAT * NIN + 255) / 256), 256, 0, stream>>>(window, x2step, t, 1);
            dc0.a0 = fullX2 ? (X2 + (size_t)t * BAT * 256) : x2step;
            dc0.lda0 = 256; dc0.len0 = 256;
            dc0.a1 = hA2[t & 1];
            dc0.W2 = W2e0; dc0.Kp = 1280;
            dc0.bih = bih0; dc0.bhh = bhh0;
            dc0.c = cA; dc0.mask_h = nullptr; dc0.mask_c = nullptr;
            dc0.h2_out = hA2[(t + 1) & 1];
            dc0.h2_aux = hd2[t & 1]; dc0.mask_aux = enc_mask + (size_t)t * SB;
            dc0.h_f32 = nullptr;
        }
        const int nz = (int)has1 + (int)has0;
        CellDesc d0 = has1 ? dc1 : dc0;
        CellDesc d1 = has0 ? dc0 : dc1;
        cell_kernel<<<dim3(4, 16, nz), block, 0, stream>>>(d0, d1);
    }

    // ---- decoder: strictly sequential ----
    for (int s = 0; s < HOR - 1; ++s) {
        proj_kernel<<<pgrid, block, 0, stream>>>(hf32, Wp, bp, pred2, out, s);
        CellDesc c1{};
        c1.a0 = pred2; c1.lda0 = 256; c1.len0 = 256;
        c1.a1 = hA2[s & 1];
        c1.W2 = W2d1; c1.Kp = 1280;
        c1.bih = bc1i; c1.bhh = bc1h;
        c1.c = cA;
        c1.mask_h = dec_h_mask + (size_t)s * SB;
        c1.mask_c = dec_c_mask + (size_t)s * SB;
        c1.h2_out = hA2[(s + 1) & 1];
        c1.h2_aux = nullptr; c1.mask_aux = nullptr; c1.h_f32 = nullptr;
        cell_kernel<<<dim3(4, 16, 1), block, 0, stream>>>(c1, c1);

        CellDesc c2{};
        c2.a0 = hA2[(s + 1) & 1]; c2.lda0 = 1024; c2.len0 = 1024;
        c2.a1 = hB2[s & 1];
        c2.W2 = W2d2; c2.Kp = 2048;
        c2.bih = bc2i; c2.bhh = bc2h;
        c2.c = cB; c2.mask_h = nullptr; c2.mask_c = nullptr;
        c2.h2_out = hB2[(s + 1) & 1];
        c2.h2_aux = nullptr; c2.mask_aux = nullptr;
        c2.h_f32 = hf32;
        cell_kernel<<<dim3(4, 16, 1), block, 0, stream>>>(c2, c2);
    }
    proj_kernel<<<pgrid, block, 0, stream>>>(hf32, Wp, bp, pred2, out, HOR - 1);
}

// Round 3
// 8668.786 us; speedup vs baseline: 2.0330x; 1.1360x over previous
//
#include <hip/hip_runtime.h>
#include <math.h>

#define HID 512
#define BAT 512
#define NIN 128
#define TST 128
#define HOR 32

using bf16x8 = __attribute__((ext_vector_type(8))) __bf16;
using f32x4  = __attribute__((ext_vector_type(4))) float;

__device__ __forceinline__ float sigf(float x) { return 1.0f / (1.0f + expf(-x)); }

__device__ __forceinline__ short f2bf(float x) {
    union { float f; unsigned u; } v; v.f = x;
    unsigned r = (v.u + 0x7FFFu + ((v.u >> 16) & 1u)) >> 16;
    return (short)r;
}
__device__ __forceinline__ float bf2f(short s) {
    union { unsigned u; float f; } v; v.u = ((unsigned)(unsigned short)s) << 16;
    return v.f;
}

__device__ __forceinline__ void async16(const void* g, void* l) {
    __builtin_amdgcn_global_load_lds(
        (const __attribute__((address_space(1))) void*)g,
        (__attribute__((address_space(3))) void*)l, 16, 0, 0);
}

// ---------------- prep kernels ----------------

// W2 row n' (permuted: n' = nb*128 + gate*32 + uu <-> orig row gate*512 + nb*32 + uu)
// cols: [0,Kx)=Wih_hi [Kx,2Kx)=Wih_lo [2Kx,2Kx+512)=Whh_hi [2Kx+512,Kp)=Whh_lo
__global__ __launch_bounds__(256) void prep_w(const float* __restrict__ Wih,
                                              const float* __restrict__ Whh,
                                              short* __restrict__ W2, int Kx, int Kp) {
    size_t i = (size_t)blockIdx.x * 256 + threadIdx.x;
    if (i >= (size_t)2048 * Kp) return;
    int np = (int)(i / Kp), kp = (int)(i % Kp);
    int nb = np >> 7, gate = (np >> 5) & 3, uu = np & 31;
    int on = gate * HID + nb * 32 + uu;
    float w; bool islo = false;
    if (kp < Kx)                { w = Wih[(size_t)on * Kx + kp]; }
    else if (kp < 2 * Kx)       { w = Wih[(size_t)on * Kx + (kp - Kx)]; islo = true; }
    else if (kp < 2 * Kx + HID) { w = Whh[(size_t)on * HID + (kp - 2 * Kx)]; }
    else                        { w = Whh[(size_t)on * HID + (kp - 2 * Kx - HID)]; islo = true; }
    short hi = f2bf(w);
    W2[i] = islo ? f2bf(w - bf2f(hi)) : hi;
}

// x2[tl][b][0..127]=hi, [128..255]=lo from window[b][t0+tl][n]
__global__ __launch_bounds__(256) void prep_x(const float* __restrict__ window,
                                              short* __restrict__ x2, int t0, int nt) {
    size_t i = (size_t)blockIdx.x * 256 + threadIdx.x;
    if (i >= (size_t)nt * BAT * NIN) return;
    int n = (int)(i & 127);
    int b = (int)((i >> 7) & 511);
    int tl = (int)(i >> 16);
    float x = window[(size_t)b * (TST * NIN) + (size_t)(t0 + tl) * NIN + n];
    short hi = f2bf(x);
    short* dst = x2 + (size_t)tl * (BAT * 256) + (size_t)b * 256;
    dst[n] = hi;
    dst[128 + n] = f2bf(x - bf2f(hi));
}

// Wfuse[on][k] = sum_n Wc1i[on][n] * Wp[n][k]   (on<2048, k<512)
__global__ __launch_bounds__(256) void prep_fuse(const float* __restrict__ Wc1i,
                                                 const float* __restrict__ Wp,
                                                 float* __restrict__ Wfuse) {
    size_t i = (size_t)blockIdx.x * 256 + threadIdx.x;
    if (i >= (size_t)2048 * 512) return;
    int on = (int)(i >> 9), k = (int)(i & 511);
    float s = 0.f;
    for (int n = 0; n < NIN; ++n) s += Wc1i[(size_t)on * NIN + n] * Wp[(size_t)n * HID + k];
    Wfuse[i] = s;
}

__global__ __launch_bounds__(256) void prep_badd(const float* __restrict__ Wc1i,
                                                 const float* __restrict__ bp,
                                                 float* __restrict__ badd) {
    int on = blockIdx.x * 256 + threadIdx.x;
    if (on >= 2048) return;
    float s = 0.f;
    for (int n = 0; n < NIN; ++n) s += Wc1i[(size_t)on * NIN + n] * bp[n];
    badd[on] = s;
}

// W2p[n][k]: [0,512)=Wp_hi, [512,1024)=Wp_lo (row-major n<128)
__global__ __launch_bounds__(256) void prep_wp(const float* __restrict__ Wp,
                                               short* __restrict__ W2p) {
    int i = blockIdx.x * 256 + threadIdx.x;
    if (i >= 128 * 1024) return;
    int n = i >> 10, k = i & 1023;
    float w = Wp[(size_t)n * HID + (k & 511)];
    short hi = f2bf(w);
    W2p[i] = (k < 512) ? hi : f2bf(w - bf2f(hi));
}

// ---------------- fused MFMA LSTM cell / projection ----------------

struct CellDesc {
    const short* a0; long lda0; int len0;  // segment 0 of A (bf16 hi|lo)
    const short* a1;                        // segment 1: recurrent h2 [B][1024]
    const short* W2; int Kp;                // permuted weights [rows][Kp]
    const float* bih; const float* bhh; const float* badd;
    float* c;                               // [B][512] in/out
    const float* mask_h; const float* mask_c;
    short* h2_out;                          // [B][1024] (mask_h applied) hi|lo
    short* h2_aux; const float* mask_aux;   // nullable: h*mask_aux hi|lo
    float* out; const float* bp; int scol;  // proj mode if out != nullptr
};

__global__ __launch_bounds__(256) void cell_kernel(CellDesc dA, CellDesc dB) {
    const CellDesc d = (blockIdx.z == 0) ? dA : dB;
    if (d.out && blockIdx.y) return;        // proj uses only n-tile 0
    __shared__ __align__(16) char smem[67584];  // 2x(A 8KB + B 8KB) dbuf; reused as gates [128][132] f32

    const int tid = threadIdx.x;
    const int m0 = blockIdx.x * 128;
    const int n0 = blockIdx.y * 128;
    const int lane = tid & 63, wid = tid >> 6;
    const int moff = (wid >> 1) * 64, noff = (wid & 1) * 64;

    f32x4 acc[4][4];
#pragma unroll
    for (int mi = 0; mi < 4; ++mi)
#pragma unroll
        for (int ni = 0; ni < 4; ++ni) acc[mi][ni] = (f32x4){0.f, 0.f, 0.f, 0.f};

    const int nkc = d.Kp >> 5;
    const int lrow = lane & 15;
    const int lko = (lane >> 4) << 4;

    auto stage = [&](int kc, int bi) {
        const int k0 = kc << 5;
        char* sb = smem + bi * 16384;
#pragma unroll
        for (int r = 0; r < 2; ++r) {
            const int idx = tid + (r << 8);
            const int row = idx >> 2;
            const int kg = k0 + ((idx & 3) << 3);
            if (k0 < d.len0)
                async16(d.a0 + (size_t)(m0 + row) * d.lda0 + kg, sb + idx * 16);
            else
                async16(d.a1 + (size_t)(m0 + row) * 1024 + (kg - d.len0), sb + idx * 16);
            async16(d.W2 + (size_t)(n0 + row) * d.Kp + kg, sb + 8192 + idx * 16);
        }
    };

    // software-pipelined K-loop: issue next tile's loads BEFORE computing current
    stage(0, 0);
    __syncthreads();
#pragma unroll 2
    for (int kc = 0; kc < nkc; ++kc) {
        const int cur = kc & 1;
        if (kc + 1 < nkc) stage(kc + 1, cur ^ 1);
        const char* sb = smem + cur * 16384;
        bf16x8 fa[4], fb[4];
#pragma unroll
        for (int mi = 0; mi < 4; ++mi)
            fa[mi] = *(const bf16x8*)(sb + (moff + mi * 16 + lrow) * 64 + lko);
#pragma unroll
        for (int ni = 0; ni < 4; ++ni)
            fb[ni] = *(const bf16x8*)(sb + 8192 + (noff + ni * 16 + lrow) * 64 + lko);
#pragma unroll
        for (int mi = 0; mi < 4; ++mi)
#pragma unroll
            for (int ni = 0; ni < 4; ++ni)
                acc[mi][ni] = __builtin_amdgcn_mfma_f32_16x16x32_bf16(fa[mi], fb[ni], acc[mi][ni], 0, 0, 0);
        __syncthreads();   // drains vmcnt(0): next tile's loads landed; cur buffer free to overwrite
    }

    // dump gates to LDS (buffers dead after final barrier)
    float* gl = (float*)smem;
#pragma unroll
    for (int mi = 0; mi < 4; ++mi)
#pragma unroll
        for (int ni = 0; ni < 4; ++ni)
#pragma unroll
            for (int r = 0; r < 4; ++r)
                gl[(moff + mi * 16 + ((lane >> 4) << 2) + r) * 132 + (noff + ni * 16 + (lane & 15))] = acc[mi][ni][r];
    __syncthreads();

    if (d.out) {  // projection epilogue: out[(b*NIN+n)*HOR + scol] = gates + bp
        const int nn = tid & 127;
        const int half = tid >> 7;
        const float bb = d.bp[nn];
#pragma unroll
        for (int i = 0; i < 64; ++i) {
            const int lb = half * 64 + i;
            d.out[((size_t)((m0 + lb) * NIN + nn)) * HOR + d.scol] = gl[(size_t)lb * 132 + nn] + bb;
        }
        return;
    }

    // LSTM pointwise epilogue: b in [m0,m0+128), u in [by*32, by*32+32)
    const int uu = tid & 31;
    const int bg = tid >> 5;
    const int u = blockIdx.y * 32 + uu;
    float bi  = d.bih[u]           + d.bhh[u];
    float bff = d.bih[HID + u]     + d.bhh[HID + u];
    float bgg = d.bih[2 * HID + u] + d.bhh[2 * HID + u];
    float boo = d.bih[3 * HID + u] + d.bhh[3 * HID + u];
    if (d.badd) {
        bi += d.badd[u]; bff += d.badd[HID + u];
        bgg += d.badd[2 * HID + u]; boo += d.badd[3 * HID + u];
    }
#pragma unroll
    for (int i = 0; i < 16; ++i) {
        const int lb = bg * 16 + i;
        const int b = m0 + lb;
        const size_t idx = (size_t)b * HID + u;
        const float* row = gl + (size_t)lb * 132;
        const float gi = row[uu] + bi;
        const float gf = row[32 + uu] + bff;
        const float gg = row[64 + uu] + bgg;
        const float go = row[96 + uu] + boo;
        const float cv = d.c[idx];
        const float cn = sigf(gf) * cv + sigf(gi) * tanhf(gg);
        const float h  = sigf(go) * tanhf(cn);
        d.c[idx] = d.mask_c ? cn * d.mask_c[idx] : cn;
        const float hm = d.mask_h ? h * d.mask_h[idx] : h;
        const short hh = f2bf(hm);
        d.h2_out[(size_t)b * 1024 + u] = hh;
        d.h2_out[(size_t)b * 1024 + HID + u] = f2bf(hm - bf2f(hh));
        if (d.h2_aux) {
            const float ha = h * d.mask_aux[idx];
            const short ah = f2bf(ha);
            d.h2_aux[(size_t)b * 1024 + u] = ah;
            d.h2_aux[(size_t)b * 1024 + HID + u] = f2bf(ha - bf2f(ah));
        }
    }
}

// ---------------- host ----------------

extern "C" void kernel_launch(void* const* d_in, const int* in_sizes, int n_in,
                              void* d_out, int out_size, void* d_ws, size_t ws_size,
                              hipStream_t stream) {
    (void)in_sizes; (void)n_in; (void)out_size;
    const float* window = (const float*)d_in[0];
    const float* Wih0 = (const float*)d_in[1];
    const float* Whh0 = (const float*)d_in[2];
    const float* bih0 = (const float*)d_in[3];
    const float* bhh0 = (const float*)d_in[4];
    const float* Wih1 = (const float*)d_in[5];
    const float* Whh1 = (const float*)d_in[6];
    const float* bih1 = (const float*)d_in[7];
    const float* bhh1 = (const float*)d_in[8];
    const float* Wc1i = (const float*)d_in[9];
    const float* Wc1h = (const float*)d_in[10];
    const float* bc1i = (const float*)d_in[11];
    const float* bc1h = (const float*)d_in[12];
    const float* Wc2i = (const float*)d_in[13];
    const float* Wc2h = (const float*)d_in[14];
    const float* bc2i = (const float*)d_in[15];
    const float* bc2h = (const float*)d_in[16];
    const float* Wp   = (const float*)d_in[17];
    const float* bp   = (const float*)d_in[18];
    const float* enc_mask   = (const float*)d_in[19];
    const float* dec_h_mask = (const float*)d_in[20];
    const float* dec_c_mask = (const float*)d_in[21];
    float* out = (float*)d_out;

    char* base = (char*)d_ws;
    size_t off = 0;
    auto take = [&](size_t bytes) -> char* {
        off = (off + 255) & ~(size_t)255;
        char* r = base + off; off += bytes; return r;
    };
    short* W2e0 = (short*)take((size_t)2048 * 1280 * 2);
    short* W2e1 = (short*)take((size_t)2048 * 2048 * 2);
    short* W2d1 = (short*)take((size_t)2048 * 2048 * 2);   // fused: [Wfuse|Wc1h] hi/lo
    short* W2d2 = (short*)take((size_t)2048 * 2048 * 2);
    short* W2p  = (short*)take((size_t)128 * 1024 * 2);
    float* Wfuse = (float*)take((size_t)2048 * 512 * 4);
    float* badd  = (float*)take((size_t)2048 * 4);
    short* hA2[2] = {(short*)take((size_t)BAT * 1024 * 2), (short*)take((size_t)BAT * 1024 * 2)};
    short* hB2[2] = {(short*)take((size_t)BAT * 1024 * 2), (short*)take((size_t)BAT * 1024 * 2)};
    short* hd2[2] = {(short*)take((size_t)BAT * 1024 * 2), (short*)take((size_t)BAT * 1024 * 2)};
    float* cA = (float*)take((size_t)BAT * HID * 4);
    float* cB = (float*)take((size_t)BAT * HID * 4);
    const size_t off_nox2 = off;
    short* X2 = (short*)take((size_t)TST * BAT * 256 * 2);
    bool fullX2 = (ws_size >= off);
    short* x2step = nullptr;
    if (!fullX2) { off = off_nox2; x2step = (short*)take((size_t)BAT * 256 * 2); }

    const size_t SB = (size_t)BAT * HID;

    // prep (re-done every call; deterministic)
    prep_fuse<<<(2048 * 512 + 255) / 256, 256, 0, stream>>>(Wc1i, Wp, Wfuse);
    prep_badd<<<8, 256, 0, stream>>>(Wc1i, bp, badd);
    prep_wp<<<(128 * 1024 + 255) / 256, 256, 0, stream>>>(Wp, W2p);
    prep_w<<<(2048 * 1280 + 255) / 256, 256, 0, stream>>>(Wih0, Whh0, W2e0, NIN, 1280);
    prep_w<<<(2048 * 2048 + 255) / 256, 256, 0, stream>>>(Wih1, Whh1, W2e1, HID, 2048);
    prep_w<<<(2048 * 2048 + 255) / 256, 256, 0, stream>>>(Wfuse, Wc1h, W2d1, HID, 2048);
    prep_w<<<(2048 * 2048 + 255) / 256, 256, 0, stream>>>(Wc2i, Wc2h, W2d2, HID, 2048);
    if (fullX2)
        prep_x<<<(int)(((size_t)TST * BAT * NIN + 255) / 256), 256, 0, stream>>>(window, X2, 0, TST);
    hipMemsetAsync(hA2[0], 0, (size_t)BAT * 1024 * 2, stream);
    hipMemsetAsync(hB2[0], 0, (size_t)BAT * 1024 * 2, stream);
    hipMemsetAsync(cA, 0, (size_t)BAT * HID * 4, stream);
    hipMemsetAsync(cB, 0, (size_t)BAT * HID * 4, stream);

    dim3 block(256);

    // ---- encoder: layer0(t) paired with layer1(t-1) in one launch ----
    for (int tt = 0; tt <= TST; ++tt) {
        const bool has1 = (tt >= 1), has0 = (tt < TST);
        CellDesc dc1{}, dc0{};
        if (has1) {
            const int t = tt - 1;
            dc1.a0 = hd2[t & 1]; dc1.lda0 = 1024; dc1.len0 = 1024;
            dc1.a1 = hB2[t & 1];
            dc1.W2 = W2e1; dc1.Kp = 2048;
            dc1.bih = bih1; dc1.bhh = bhh1; dc1.badd = nullptr;
            dc1.c = cB;
            dc1.h2_out = hB2[(t + 1) & 1];
        }
        if (has0) {
            const int t = tt;
            if (!fullX2)
                prep_x<<<(int)(((size_t)BAT * NIN + 255) / 256), 256, 0, stream>>>(window, x2step, t, 1);
            dc0.a0 = fullX2 ? (X2 + (size_t)t * BAT * 256) : x2step;
            dc0.lda0 = 256; dc0.len0 = 256;
            dc0.a1 = hA2[t & 1];
            dc0.W2 = W2e0; dc0.Kp = 1280;
            dc0.bih = bih0; dc0.bhh = bhh0; dc0.badd = nullptr;
            dc0.c = cA;
            dc0.h2_out = hA2[(t + 1) & 1];
            dc0.h2_aux = hd2[t & 1]; dc0.mask_aux = enc_mask + (size_t)t * SB;
        }
        const int nz = (int)has1 + (int)has0;
        CellDesc d0 = has1 ? dc1 : dc0;
        CellDesc d1 = has0 ? dc0 : dc1;
        cell_kernel<<<dim3(4, 16, nz), block, 0, stream>>>(d0, d1);
    }

    // ---- decoder: per step {cell1(fused proj-weights) ∥ proj(out col)} then cell2 ----
    for (int s = 0; s < HOR; ++s) {
        CellDesc pj{};
        pj.a0 = hB2[s & 1]; pj.lda0 = 1024; pj.len0 = 1024;
        pj.W2 = W2p; pj.Kp = 1024;
        pj.out = out; pj.bp = bp; pj.scol = s;
        if (s == HOR - 1) {
            cell_kernel<<<dim3(4, 1, 1), block, 0, stream>>>(pj, pj);
            break;
        }
        CellDesc c1{};
        c1.a0 = hB2[s & 1]; c1.lda0 = 1024; c1.len0 = 1024;   // h2 drives fused (Wc1i@Wp) term
        c1.a1 = hA2[s & 1];
        c1.W2 = W2d1; c1.Kp = 2048;
        c1.bih = bc1i; c1.bhh = bc1h; c1.badd = badd;
        c1.c = cA;
        c1.mask_h = dec_h_mask + (size_t)s * SB;
        c1.mask_c = dec_c_mask + (size_t)s * SB;
        c1.h2_out = hA2[(s + 1) & 1];
        cell_kernel<<<dim3(4, 16, 2), block, 0, stream>>>(c1, pj);

        CellDesc c2{};
        c2.a0 = hA2[(s + 1) & 1]; c2.lda0 = 1024; c2.len0 = 1024;
        c2.a1 = hB2[s & 1];
        c2.W2 = W2d2; c2.Kp = 2048;
        c2.bih = bc2i; c2.bhh = bc2h; c2.badd = nullptr;
        c2.c = cB;
        c2.h2_out = hB2[(s + 1) & 1];
        cell_kernel<<<dim3(4, 16, 1), block, 0, stream>>>(c2, c2);
    }
}